// Round 14
// baseline (335.446 us; speedup 1.0000x reference)
//
#include <hip/hip_runtime.h>
#include <hip/hip_bf16.h>

typedef unsigned short u16;
typedef unsigned int   u32;
typedef __attribute__((ext_vector_type(2))) float f32x2;

__device__ __forceinline__ float bf2f(u32 bits) { return __uint_as_float(bits << 16); }
__device__ __forceinline__ u32 f2bf_bits(float x) {           // RNE, finite inputs
    u32 u = __float_as_uint(x);
    return (u + 0x7fffu + ((u >> 16) & 1u)) >> 16;
}
// raw v_exp_f32 (2^x): pure asm (no volatile -> CSE-able); CDNA interlocks cover latency
__device__ __forceinline__ float exp2_raw(float x) {
    float r; asm("v_exp_f32 %0, %1" : "=v"(r) : "v"(x)); return r;
}

// ---------------- fused: zero(deg) + dtype detect + param conversion ----------------
// al/ar pre-scaled by log2(e): score kernels use raw v_exp_f32 (2^x) directly.
__global__ __launch_bounds__(256) void cvt_zero_det(
    const u32* __restrict__ hw,
    const void* __restrict__ W0, const void* __restrict__ al0, const void* __restrict__ ar0, const void* __restrict__ b0,
    const void* __restrict__ W1, const void* __restrict__ al1, const void* __restrict__ ar1, const void* __restrict__ b1,
    const void* __restrict__ W2, const void* __restrict__ al2, const void* __restrict__ ar2, const void* __restrict__ b2,
    float* __restrict__ P, int* __restrict__ flag, int* __restrict__ deg, int NP)
{
    int t = threadIdx.x;
    int gstr = gridDim.x * 256;
    for (int z = blockIdx.x * 256 + t; z < NP; z += gstr) deg[z] = 0;

    if (blockIdx.x >= 67) return;          // block-uniform exit: no barrier hazard

    __shared__ int s_hit;
    if (t == 0) s_hit = 0;
    __syncthreads();
    int hit = 0;
    for (int i = t; i < 8192; i += 256) {
        u32 lo = hw[i] & 0xffffu;
        if (((lo >> 7) & 0xffu) == 0xffu) hit = 1;
    }
    if (hit) atomicOr(&s_hit, 1);
    __syncthreads();
    int f32in = s_hit;
    if (blockIdx.x == 0 && t == 0) *flag = f32in;

    int i = blockIdx.x * 256 + t;
    const void* s; int off;
    if      (i < 8192)  { s = W0;  off = 0;     }
    else if (i < 12288) { s = W1;  off = 8192;  }
    else if (i < 16384) { s = W2;  off = 12288; }
    else if (i < 16448) { s = al0; off = 16384; }
    else if (i < 16512) { s = ar0; off = 16448; }
    else if (i < 16576) { s = b0;  off = 16512; }
    else if (i < 16640) { s = al1; off = 16576; }
    else if (i < 16704) { s = ar1; off = 16640; }
    else if (i < 16768) { s = b1;  off = 16704; }
    else if (i < 16832) { s = al2; off = 16768; }
    else if (i < 16896) { s = ar2; off = 16832; }
    else if (i < 16960) { s = b2;  off = 16896; }
    else return;
    int j = i - off;
    float v = f32in ? ((const float*)s)[j] : bf2f(((const u16*)s)[j]);
    bool is_attn = (i >= 16384) && !((i >= 16512 && i < 16576) ||   // b0
                                     (i >= 16704 && i < 16768) ||   // b1
                                     (i >= 16896));                 // b2
    if (is_attn) v *= 1.44269504088896340736f;
    P[i] = v;
}

// ---------------- CSR build ----------------
__global__ __launch_bounds__(256) void hist_rank(
    const int* __restrict__ dst, int* __restrict__ deg, int* __restrict__ rank, int E)
{
    int e = blockIdx.x * 256 + threadIdx.x;
    if (e < E) rank[e] = atomicAdd(&deg[dst[e]], 1);
}

// fused scan: block c derives its chunk-prefix directly from deg, then local scan.
__global__ __launch_bounds__(256) void scan_all(
    const int* __restrict__ deg, int* __restrict__ row_start)
{
    __shared__ int sm[256];
    int t = threadIdx.x;
    int c = blockIdx.x;

    int pre = 0;
    int nInt4 = c * 256;
    const int4* dp = (const int4*)deg;
    for (int j = t; j < nInt4; j += 256) {
        int4 v = dp[j];
        pre += v.x + v.y + v.z + v.w;
    }
    sm[t] = pre;
    __syncthreads();
#pragma unroll
    for (int off = 128; off; off >>= 1) {
        if (t < off) sm[t] += sm[t + off];
        __syncthreads();
    }
    int base = sm[0];
    __syncthreads();

    size_t boff = (size_t)c * 1024;
    int4 v = ((const int4*)(deg + boff))[t];
    int tsum = v.x + v.y + v.z + v.w;
    sm[t] = tsum;
    __syncthreads();
#pragma unroll
    for (int off = 1; off < 256; off <<= 1) {
        int a = (t >= off) ? sm[t - off] : 0;
        __syncthreads();
        sm[t] += a;
        __syncthreads();
    }
    int excl = sm[t] - tsum + base;
    int4 r;
    r.x = excl;
    r.y = excl + v.x;
    r.z = excl + v.x + v.y;
    r.w = excl + v.x + v.y + v.z;
    ((int4*)(row_start + boff))[t] = r;
}

__global__ __launch_bounds__(256) void scatter_kernel(
    const int* __restrict__ src, const int* __restrict__ dst, const int* __restrict__ rank,
    const int* __restrict__ row_start, int* __restrict__ csr_src, int E)
{
    int e = blockIdx.x * 256 + threadIdx.x;
    if (e < E) csr_src[row_start[dst[e]] + rank[e]] = src[e];
}

// ---------------- GEMM + attention dots ----------------
template<int F_IN, int H, bool LAYER0>
__global__ __launch_bounds__(256) void gemm_attn(
    const int* __restrict__ flag, const void* __restrict__ xv,
    const float* __restrict__ Wf, const float* __restrict__ alf, const float* __restrict__ arf,
    u16* __restrict__ fo, float* __restrict__ el, float* __restrict__ er, int N)
{
    int lane = threadIdx.x & 63;
    int cg   = __builtin_amdgcn_readfirstlane(threadIdx.x >> 6);   // 0..3
    int n    = blockIdx.x * 64 + lane;
    bool act = (n < N);

    float acc[16];
#pragma unroll
    for (int c = 0; c < 16; c++) acc[c] = 0.f;

    const float* Wcol = Wf + cg * 16;
    bool f32in = LAYER0 ? (*flag != 0) : false;

    if (act) {
        if (f32in) {
            const float* x = (const float*)xv + (size_t)n * F_IN;
            for (int k0 = 0; k0 < F_IN; k0 += 4) {
                float4 u = *reinterpret_cast<const float4*>(x + k0);
                float xs[4] = {u.x, u.y, u.z, u.w};
#pragma unroll
                for (int j = 0; j < 4; j++) {
                    const float* w = Wcol + (size_t)(k0 + j) * 64;   // scalar loads
#pragma unroll
                    for (int c = 0; c < 16; c++) acc[c] = fmaf(xs[j], w[c], acc[c]);
                }
            }
        } else {
            const u16* x = (const u16*)xv + (size_t)n * F_IN;
            for (int k0 = 0; k0 < F_IN; k0 += 8) {
                uint4 u = *reinterpret_cast<const uint4*>(x + k0);
                float xs[8];
                xs[0] = bf2f(u.x & 0xffffu); xs[1] = bf2f(u.x >> 16);
                xs[2] = bf2f(u.y & 0xffffu); xs[3] = bf2f(u.y >> 16);
                xs[4] = bf2f(u.z & 0xffffu); xs[5] = bf2f(u.z >> 16);
                xs[6] = bf2f(u.w & 0xffffu); xs[7] = bf2f(u.w >> 16);
#pragma unroll
                for (int j = 0; j < 8; j++) {
                    const float* w = Wcol + (size_t)(k0 + j) * 64;
#pragma unroll
                    for (int c = 0; c < 16; c++) acc[c] = fmaf(xs[j], w[c], acc[c]);
                }
            }
        }
    }

    float e1 = 0.f, e2 = 0.f;
#pragma unroll
    for (int c = 0; c < 16; c++) {
        e1 = fmaf(acc[c], alf[cg * 16 + c], e1);
        e2 = fmaf(acc[c], arf[cg * 16 + c], e2);
    }
    if constexpr (H == 4) {
        if (act) {
            el[(size_t)n * 4 + cg] = e1;
            er[(size_t)n * 4 + cg] = e2;
        }
    } else {
        __shared__ float sel[4][64];
        __shared__ float ser[4][64];
        sel[cg][lane] = e1;
        ser[cg][lane] = e2;
        __syncthreads();
        if (cg == 0 && act) {
            el[n] = sel[0][lane] + sel[1][lane] + sel[2][lane] + sel[3][lane];
            er[n] = ser[0][lane] + ser[1][lane] + ser[2][lane] + ser[3][lane];
        }
    }

    if (act) {
        u16* dp = fo + (size_t)n * 64 + cg * 16;
        uint4 v;
        v.x = f2bf_bits(acc[0])  | (f2bf_bits(acc[1])  << 16);
        v.y = f2bf_bits(acc[2])  | (f2bf_bits(acc[3])  << 16);
        v.z = f2bf_bits(acc[4])  | (f2bf_bits(acc[5])  << 16);
        v.w = f2bf_bits(acc[6])  | (f2bf_bits(acc[7])  << 16);
        *reinterpret_cast<uint4*>(dp) = v;
        v.x = f2bf_bits(acc[8])  | (f2bf_bits(acc[9])  << 16);
        v.y = f2bf_bits(acc[10]) | (f2bf_bits(acc[11]) << 16);
        v.z = f2bf_bits(acc[12]) | (f2bf_bits(acc[13]) << 16);
        v.w = f2bf_bits(acc[14]) | (f2bf_bits(acc[15]) << 16);
        *reinterpret_cast<uint4*>(dp + 8) = v;
    }
}

// ---------------- edge-parallel exp-score kernel ----------------
// One thread per (edge, head): computes exp2(lrelu(el[src]+er[dst])) ONCE and
// scatters it into CSR slot order (same slot formula as scatter_kernel).
// Removes the 16x-duplicated score chain (incl. quarter-rate v_exp) from
// aggregate's feature lanes. H=4: 4 threads/edge write a 16B-contiguous group.
template<int H>
__global__ __launch_bounds__(256) void edge_scores(
    const int* __restrict__ src, const int* __restrict__ dst,
    const int* __restrict__ rank, const int* __restrict__ row_start,
    const float* __restrict__ el, const float* __restrict__ er,
    float* __restrict__ w, int E)
{
    int t = blockIdx.x * 256 + threadIdx.x;
    int e = (H == 4) ? (t >> 2) : t;
    if (e >= E) return;
    int s = src[e], d = dst[e];
    int slot = row_start[d] + rank[e];
    if constexpr (H == 4) {
        int h = t & 3;
        float sc = el[(s << 2) + h] + er[(d << 2) + h];
        sc = fmaxf(sc, 0.2f * sc);
        w[(slot << 2) + h] = exp2_raw(sc);
    } else {
        float sc = el[s] + er[d];
        sc = fmaxf(sc, 0.2f * sc);
        w[slot] = exp2_raw(sc);
    }
}

// ---------------- aggregation: precomputed scores + feature gather ----------------
// Per edge now just: w load (H=1: wave-uniform -> s_load) + fo row gather +
// pk add/fma. exp, lrelu, el/er reads all moved to edge_scores.
template<int H, bool FINAL>
__global__ __launch_bounds__(256) void aggregate(
    const int* __restrict__ flag,
    const u16* __restrict__ fo, const float* __restrict__ w,
    const int* __restrict__ row_start, const int* __restrict__ csr_src,
    const float* __restrict__ bias, void* __restrict__ outp, int N)
{
    int gid  = blockIdx.x * 256 + threadIdx.x;
    int n    = __builtin_amdgcn_readfirstlane(gid >> 6);   // wave-uniform node id
    int lane = threadIdx.x & 63;
    if (n >= N) return;
    constexpr int D = 64 / H;
    int h = lane / D;
    int i0 = __builtin_amdgcn_readfirstlane(row_start[n]);
    int i1 = __builtin_amdgcn_readfirstlane(row_start[n + 1]);

    f32x2 sAcc = {0.f, 0.f};
    f32x2 aAcc = {0.f, 0.f};
    float s0 = 0.f, a0 = 0.f;
    int i = i0;

    for (; i + 8 <= i1; i += 8) {
        int s[8];
#pragma unroll
        for (int j = 0; j < 8; j++) s[j] = __builtin_amdgcn_readfirstlane(csr_src[i + j]);
        float wv[8], fv[8];
#pragma unroll
        for (int j = 0; j < 8; j++)
            wv[j] = (H == 4) ? w[((i + j) << 2) + h] : w[i + j];
#pragma unroll
        for (int j = 0; j < 8; j++) fv[j] = bf2f((fo + ((size_t)s[j] << 6))[lane]);
#pragma unroll
        for (int j = 0; j < 8; j += 2) {
            f32x2 w2 = {wv[j], wv[j + 1]};
            f32x2 f2 = {fv[j], fv[j + 1]};
            sAcc += w2;
            aAcc = w2 * f2 + aAcc;
        }
    }
    for (; i + 4 <= i1; i += 4) {
        int s[4];
#pragma unroll
        for (int j = 0; j < 4; j++) s[j] = __builtin_amdgcn_readfirstlane(csr_src[i + j]);
        float wv[4], fv[4];
#pragma unroll
        for (int j = 0; j < 4; j++)
            wv[j] = (H == 4) ? w[((i + j) << 2) + h] : w[i + j];
#pragma unroll
        for (int j = 0; j < 4; j++) fv[j] = bf2f((fo + ((size_t)s[j] << 6))[lane]);
#pragma unroll
        for (int j = 0; j < 4; j += 2) {
            f32x2 w2 = {wv[j], wv[j + 1]};
            f32x2 f2 = {fv[j], fv[j + 1]};
            sAcc += w2;
            aAcc = w2 * f2 + aAcc;
        }
    }
    for (; i < i1; i++) {
        int s = __builtin_amdgcn_readfirstlane(csr_src[i]);
        float wvv = (H == 4) ? w[(i << 2) + h] : w[i];
        float fv = bf2f((fo + ((size_t)s << 6))[lane]);
        s0 += wvv;
        a0 = fmaf(wvv, fv, a0);
    }

    float sumex = (sAcc.x + sAcc.y) + s0;
    float acc   = (aAcc.x + aAcc.y) + a0;
    float o;
    if (i1 > i0) o = acc * __builtin_amdgcn_rcpf(sumex) + bias[lane];   // v_rcp: ~1ulp, tol 3.9e-3
    else         o = bias[lane];                                        // 0-in-degree -> bias
    size_t idx = (size_t)n * 64 + lane;
    if constexpr (!FINAL) {
        // ELU: expm1(o) = 2^(o*log2e) - 1 (cancellation abs err ~6e-8, OK at bf16 out)
        float t = exp2_raw(o * 1.44269504088896340736f);
        o = o > 0.f ? o : (t - 1.f);
        ((u16*)outp)[idx] = f2bf_bits(o);
    } else {
        if (*flag) ((float*)outp)[idx] = o;
        else       ((u16*)outp)[idx]   = f2bf_bits(o);
    }
}

extern "C" void kernel_launch(void* const* d_in, const int* in_sizes, int n_in,
                              void* d_out, int out_size, void* d_ws, size_t ws_size,
                              hipStream_t stream)
{
    const void* h    = d_in[0];
    const int*  srcp = (const int*)d_in[1];
    const int*  dstp = (const int*)d_in[2];

    const int N  = in_sizes[0] / 128;
    const int E  = in_sizes[1];
    const int NP = (N + 1024) & ~1023;     // multiple of 1024, always covers N+1
    const int B  = NP / 1024;              // scan blocks

    // ---- workspace carve-out ----
    char* ws = (char*)d_ws;
    size_t off = 0;
    auto take = [&](size_t bytes) -> char* {
        char* p = ws + off;
        off = (off + bytes + 255) & ~(size_t)255;
        return p;
    };
    float* P         = (float*)take(16960 * 4);
    int*   flag      = (int*)  take(256);
    float* el        = (float*)take((size_t)N * 4 * 4);
    float* er        = (float*)take((size_t)N * 4 * 4);
    int*   deg       = (int*)  take((size_t)NP * 4);
    int*   row_start = (int*)  take((size_t)NP * 4);   // covers N+1
    int*   rank      = (int*)  take((size_t)E * 4);
    int*   csr_src   = (int*)  take((size_t)E * 4);
    u16*   f         = (u16*)  take((size_t)N * 64 * 2);   // bf16 activations
    u16*   x1        = (u16*)  take((size_t)N * 64 * 2);
    if (off > ws_size) x1 = (u16*)d_out;   // legacy fallback (consumed before final write)

    // w4 (E*4 floats, layers 0/1): try ws, else d_out (idle until final write;
    // w4 is dead before the final aggregate writes d_out).
    size_t off_before_w4 = off;
    float* w4 = (float*)take((size_t)E * 4 * 4);
    if (off > ws_size) { w4 = (float*)d_out; off = off_before_w4; }
    // w1 (E floats, layer 2): reuse rank (dead after CSR build... but edge_scores
    // READS rank! rank is needed by edge_scores<1>. Use deg instead? deg (NP ints)
    // too small (NP << E). Carve from ws if room, else alias csr-safe region:
    // NOT rank. Fall back to w4's space (w4 dead after layer-1 aggregate).
    size_t off_before_w1 = off;
    float* w1 = (float*)take((size_t)E * 4);
    if (off > ws_size) { w1 = w4; off = off_before_w1; }   // w4 dead by layer 2; if w4==d_out, final agg writes after w1 reads complete within same kernel? NO - same kernel reads w1 and writes d_out. Safe only if w4 != d_out region overlap... see note below.
    // Safety: if w1 aliases w4 AND w4 aliases d_out, the final aggregate would
    // read w1 from d_out while writing d_out. Slot i is read before out[n] is
    // written only within the same wave; different waves race. Avoid: if w4 is
    // d_out, put w1 in the f buffer? f is LIVE in final aggregate (fo). el/er
    // are dead in layer 2 (size N*16B = 800KB < E*4B=3.2MB: too small). rank is
    // read by edge_scores<1> itself but dead AFTER it: edge_scores reads rank,
    // writes w1 -> cannot alias. csr_src live. Last resort: reuse el..csr_src
    // region? Simplest correct: w1 = x1 region AFTER layer-2 gemm consumed x1?
    // x1 (N*64*2B = 6.4MB > 3.2MB) is dead once gemm_attn layer-2 has read it,
    // which completes before edge_scores<1> launches. Use x1 (if x1 in ws).
    if (w1 == w4 && (void*)w4 == d_out) w1 = (float*)x1;   // x1 dead after gemm2

    float* Wf0  = P;          float* Wf1  = P + 8192;  float* Wf2  = P + 12288;
    float* alf0 = P + 16384;  float* arf0 = P + 16448; float* bf0  = P + 16512;
    float* alf1 = P + 16576;  float* arf1 = P + 16640; float* bf1  = P + 16704;
    float* alf2 = P + 16768;  float* arf2 = P + 16832; float* bf2  = P + 16896;

    // 1) zero(deg) + dtype detect + param conversion, fused
    int cz_blocks = (NP + 255) / 256;
    if (cz_blocks < 67) cz_blocks = 67;
    cvt_zero_det<<<cz_blocks, 256, 0, stream>>>((const u32*)h,
        d_in[3], d_in[4], d_in[5], d_in[6],
        d_in[7], d_in[8], d_in[9], d_in[10],
        d_in[11], d_in[12], d_in[13], d_in[14], P, flag, deg, NP);

    // 2) CSR build: hist -> fused scan -> scatter
    hist_rank<<<(E + 255) / 256, 256, 0, stream>>>(dstp, deg, rank, E);
    scan_all<<<B, 256, 0, stream>>>(deg, row_start);
    scatter_kernel<<<(E + 255) / 256, 256, 0, stream>>>(srcp, dstp, rank, row_start, csr_src, E);

    int gemm_blocks = (N + 63) / 64;          // 4 waves/block, 16 cols each
    int agg_blocks  = (N * 64 + 255) / 256;   // one 64-lane wave per node
    int sc4_blocks  = (E * 4 + 255) / 256;    // edge_scores<4>
    int sc1_blocks  = (E + 255) / 256;        // edge_scores<1>

    // layer 0: 128 -> 4x16
    gemm_attn<128, 4, true ><<<gemm_blocks, 256, 0, stream>>>(flag, h,  Wf0, alf0, arf0, f, el, er, N);
    edge_scores<4><<<sc4_blocks, 256, 0, stream>>>(srcp, dstp, rank, row_start, el, er, w4, E);
    aggregate<4, false><<<agg_blocks, 256, 0, stream>>>(flag, f, w4, row_start, csr_src, bf0, x1, N);
    // layer 1: 64 -> 4x16
    gemm_attn<64, 4, false><<<gemm_blocks, 256, 0, stream>>>(flag, x1, Wf1, alf1, arf1, f, el, er, N);
    edge_scores<4><<<sc4_blocks, 256, 0, stream>>>(srcp, dstp, rank, row_start, el, er, w4, E);
    aggregate<4, false><<<agg_blocks, 256, 0, stream>>>(flag, f, w4, row_start, csr_src, bf1, x1, N);
    // layer 2: 64 -> 1x64 (final)
    gemm_attn<64, 1, false><<<gemm_blocks, 256, 0, stream>>>(flag, x1, Wf2, alf2, arf2, f, el, er, N);
    edge_scores<1><<<sc1_blocks, 256, 0, stream>>>(srcp, dstp, rank, row_start, el, er, w1, E);
    aggregate<1, true ><<<agg_blocks, 256, 0, stream>>>(flag, f, w1, row_start, csr_src, bf2, d_out, N);
}

// Round 15
// 294.313 us; speedup vs baseline: 1.1398x; 1.1398x over previous
//
#include <hip/hip_runtime.h>
#include <hip/hip_bf16.h>

typedef unsigned short u16;
typedef unsigned int   u32;

__device__ __forceinline__ float bf2f(u32 bits) { return __uint_as_float(bits << 16); }
__device__ __forceinline__ u32 f2bf_bits(float x) {           // RNE, finite inputs
    u32 u = __float_as_uint(x);
    return (u + 0x7fffu + ((u >> 16) & 1u)) >> 16;
}
// raw v_exp_f32 (2^x): pure asm (no volatile -> CSE-able); CDNA interlocks cover latency
__device__ __forceinline__ float exp2_raw(float x) {
    float r; asm("v_exp_f32 %0, %1" : "=v"(r) : "v"(x)); return r;
}

// ---------------- fused: zero(deg) + dtype detect + param conversion ----------------
// al/ar pre-scaled by log2(e): aggregate uses raw v_exp_f32 (2^x) directly.
__global__ __launch_bounds__(256) void cvt_zero_det(
    const u32* __restrict__ hw,
    const void* __restrict__ W0, const void* __restrict__ al0, const void* __restrict__ ar0, const void* __restrict__ b0,
    const void* __restrict__ W1, const void* __restrict__ al1, const void* __restrict__ ar1, const void* __restrict__ b1,
    const void* __restrict__ W2, const void* __restrict__ al2, const void* __restrict__ ar2, const void* __restrict__ b2,
    float* __restrict__ P, int* __restrict__ flag, int* __restrict__ deg, int NP)
{
    int t = threadIdx.x;
    int gstr = gridDim.x * 256;
    for (int z = blockIdx.x * 256 + t; z < NP; z += gstr) deg[z] = 0;

    if (blockIdx.x >= 67) return;          // block-uniform exit: no barrier hazard

    __shared__ int s_hit;
    if (t == 0) s_hit = 0;
    __syncthreads();
    int hit = 0;
    for (int i = t; i < 8192; i += 256) {
        u32 lo = hw[i] & 0xffffu;
        if (((lo >> 7) & 0xffu) == 0xffu) hit = 1;
    }
    if (hit) atomicOr(&s_hit, 1);
    __syncthreads();
    int f32in = s_hit;
    if (blockIdx.x == 0 && t == 0) *flag = f32in;

    int i = blockIdx.x * 256 + t;
    const void* s; int off;
    if      (i < 8192)  { s = W0;  off = 0;     }
    else if (i < 12288) { s = W1;  off = 8192;  }
    else if (i < 16384) { s = W2;  off = 12288; }
    else if (i < 16448) { s = al0; off = 16384; }
    else if (i < 16512) { s = ar0; off = 16448; }
    else if (i < 16576) { s = b0;  off = 16512; }
    else if (i < 16640) { s = al1; off = 16576; }
    else if (i < 16704) { s = ar1; off = 16640; }
    else if (i < 16768) { s = b1;  off = 16704; }
    else if (i < 16832) { s = al2; off = 16768; }
    else if (i < 16896) { s = ar2; off = 16832; }
    else if (i < 16960) { s = b2;  off = 16896; }
    else return;
    int j = i - off;
    float v = f32in ? ((const float*)s)[j] : bf2f(((const u16*)s)[j]);
    bool is_attn = (i >= 16384) && !((i >= 16512 && i < 16576) ||   // b0
                                     (i >= 16704 && i < 16768) ||   // b1
                                     (i >= 16896));                 // b2
    if (is_attn) v *= 1.44269504088896340736f;
    P[i] = v;
}

// ---------------- CSR build ----------------
__global__ __launch_bounds__(256) void hist_rank(
    const int* __restrict__ dst, int* __restrict__ deg, int* __restrict__ rank, int E)
{
    int e = blockIdx.x * 256 + threadIdx.x;
    if (e < E) rank[e] = atomicAdd(&deg[dst[e]], 1);
}

// fused scan: block c derives its chunk-prefix directly from deg, then local scan.
__global__ __launch_bounds__(256) void scan_all(
    const int* __restrict__ deg, int* __restrict__ row_start)
{
    __shared__ int sm[256];
    int t = threadIdx.x;
    int c = blockIdx.x;

    int pre = 0;
    int nInt4 = c * 256;
    const int4* dp = (const int4*)deg;
    for (int j = t; j < nInt4; j += 256) {
        int4 v = dp[j];
        pre += v.x + v.y + v.z + v.w;
    }
    sm[t] = pre;
    __syncthreads();
#pragma unroll
    for (int off = 128; off; off >>= 1) {
        if (t < off) sm[t] += sm[t + off];
        __syncthreads();
    }
    int base = sm[0];
    __syncthreads();

    size_t boff = (size_t)c * 1024;
    int4 v = ((const int4*)(deg + boff))[t];
    int tsum = v.x + v.y + v.z + v.w;
    sm[t] = tsum;
    __syncthreads();
#pragma unroll
    for (int off = 1; off < 256; off <<= 1) {
        int a = (t >= off) ? sm[t - off] : 0;
        __syncthreads();
        sm[t] += a;
        __syncthreads();
    }
    int excl = sm[t] - tsum + base;
    int4 r;
    r.x = excl;
    r.y = excl + v.x;
    r.z = excl + v.x + v.y;
    r.w = excl + v.x + v.y + v.z;
    ((int4*)(row_start + boff))[t] = r;
}

__global__ __launch_bounds__(256) void scatter_kernel(
    const int* __restrict__ src, const int* __restrict__ dst, const int* __restrict__ rank,
    const int* __restrict__ row_start, int* __restrict__ csr_src, int E)
{
    int e = blockIdx.x * 256 + threadIdx.x;
    if (e < E) csr_src[row_start[dst[e]] + rank[e]] = src[e];
}

// ---------------- GEMM + attention dots ----------------
template<int F_IN, int H, bool LAYER0>
__global__ __launch_bounds__(256) void gemm_attn(
    const int* __restrict__ flag, const void* __restrict__ xv,
    const float* __restrict__ Wf, const float* __restrict__ alf, const float* __restrict__ arf,
    u16* __restrict__ fo, float* __restrict__ el, float* __restrict__ er, int N)
{
    int lane = threadIdx.x & 63;
    int cg   = __builtin_amdgcn_readfirstlane(threadIdx.x >> 6);   // 0..3
    int n    = blockIdx.x * 64 + lane;
    bool act = (n < N);

    float acc[16];
#pragma unroll
    for (int c = 0; c < 16; c++) acc[c] = 0.f;

    const float* Wcol = Wf + cg * 16;
    bool f32in = LAYER0 ? (*flag != 0) : false;

    if (act) {
        if (f32in) {
            const float* x = (const float*)xv + (size_t)n * F_IN;
            for (int k0 = 0; k0 < F_IN; k0 += 4) {
                float4 u = *reinterpret_cast<const float4*>(x + k0);
                float xs[4] = {u.x, u.y, u.z, u.w};
#pragma unroll
                for (int j = 0; j < 4; j++) {
                    const float* w = Wcol + (size_t)(k0 + j) * 64;   // scalar loads
#pragma unroll
                    for (int c = 0; c < 16; c++) acc[c] = fmaf(xs[j], w[c], acc[c]);
                }
            }
        } else {
            const u16* x = (const u16*)xv + (size_t)n * F_IN;
            for (int k0 = 0; k0 < F_IN; k0 += 8) {
                uint4 u = *reinterpret_cast<const uint4*>(x + k0);
                float xs[8];
                xs[0] = bf2f(u.x & 0xffffu); xs[1] = bf2f(u.x >> 16);
                xs[2] = bf2f(u.y & 0xffffu); xs[3] = bf2f(u.y >> 16);
                xs[4] = bf2f(u.z & 0xffffu); xs[5] = bf2f(u.z >> 16);
                xs[6] = bf2f(u.w & 0xffffu); xs[7] = bf2f(u.w >> 16);
#pragma unroll
                for (int j = 0; j < 8; j++) {
                    const float* w = Wcol + (size_t)(k0 + j) * 64;
#pragma unroll
                    for (int c = 0; c < 16; c++) acc[c] = fmaf(xs[j], w[c], acc[c]);
                }
            }
        }
    }

    float e1 = 0.f, e2 = 0.f;
#pragma unroll
    for (int c = 0; c < 16; c++) {
        e1 = fmaf(acc[c], alf[cg * 16 + c], e1);
        e2 = fmaf(acc[c], arf[cg * 16 + c], e2);
    }
    if constexpr (H == 4) {
        if (act) {
            el[(size_t)n * 4 + cg] = e1;
            er[(size_t)n * 4 + cg] = e2;
        }
    } else {
        __shared__ float sel[4][64];
        __shared__ float ser[4][64];
        sel[cg][lane] = e1;
        ser[cg][lane] = e2;
        __syncthreads();
        if (cg == 0 && act) {
            el[n] = sel[0][lane] + sel[1][lane] + sel[2][lane] + sel[3][lane];
            er[n] = ser[0][lane] + ser[1][lane] + ser[2][lane] + ser[3][lane];
        }
    }

    if (act) {
        u16* dp = fo + (size_t)n * 64 + cg * 16;
        uint4 v;
        v.x = f2bf_bits(acc[0])  | (f2bf_bits(acc[1])  << 16);
        v.y = f2bf_bits(acc[2])  | (f2bf_bits(acc[3])  << 16);
        v.z = f2bf_bits(acc[4])  | (f2bf_bits(acc[5])  << 16);
        v.w = f2bf_bits(acc[6])  | (f2bf_bits(acc[7])  << 16);
        *reinterpret_cast<uint4*>(dp) = v;
        v.x = f2bf_bits(acc[8])  | (f2bf_bits(acc[9])  << 16);
        v.y = f2bf_bits(acc[10]) | (f2bf_bits(acc[11]) << 16);
        v.z = f2bf_bits(acc[12]) | (f2bf_bits(acc[13]) << 16);
        v.w = f2bf_bits(acc[14]) | (f2bf_bits(acc[15]) << 16);
        *reinterpret_cast<uint4*>(dp + 8) = v;
    }
}

// ---------------- wave-per-node softmax aggregation ----------------
// R10 final form: scalar backbone (rfl -> SGPR addressing, VGPR=20), raw
// v_exp_f32 (input pre-scaled by log2e), rcp divide, exp2-based ELU, 8-wide
// unroll. Session-best 295.3 us; 5 structural restructures (R7/R9/R12/R13/R14)
// all failed to beat this issue-bound floor.
template<int H, bool FINAL>
__global__ __launch_bounds__(256) void aggregate(
    const int* __restrict__ flag,
    const u16* __restrict__ fo, const float* __restrict__ el, const float* __restrict__ er,
    const int* __restrict__ row_start, const int* __restrict__ csr_src,
    const float* __restrict__ bias, void* __restrict__ outp, int N)
{
    int gid  = blockIdx.x * 256 + threadIdx.x;
    int n    = __builtin_amdgcn_readfirstlane(gid >> 6);   // wave-uniform node id
    int lane = threadIdx.x & 63;
    if (n >= N) return;
    constexpr int D = 64 / H;
    int h = lane / D;
    float erh = er[n * H + h];
    int i0 = __builtin_amdgcn_readfirstlane(row_start[n]);
    int i1 = __builtin_amdgcn_readfirstlane(row_start[n + 1]);
    float s0 = 0.f, s1 = 0.f, a0 = 0.f, a1 = 0.f;
    int i = i0;

    for (; i + 8 <= i1; i += 8) {
        int s[8];
#pragma unroll
        for (int j = 0; j < 8; j++) s[j] = __builtin_amdgcn_readfirstlane(csr_src[i + j]);
        float ev[8], fv[8];
#pragma unroll
        for (int j = 0; j < 8; j++) ev[j] = (el + s[j] * H)[h];          // uniform base + h*4
#pragma unroll
        for (int j = 0; j < 8; j++) fv[j] = bf2f((fo + ((size_t)s[j] << 6))[lane]);
#pragma unroll
        for (int j = 0; j < 8; j++) {
            float v = ev[j] + erh;
            v = fmaxf(v, 0.2f * v);
            float ex = exp2_raw(v);
            if (j & 1) { s1 += ex; a1 = fmaf(ex, fv[j], a1); }
            else       { s0 += ex; a0 = fmaf(ex, fv[j], a0); }
        }
    }
    for (; i + 4 <= i1; i += 4) {
        int s[4];
#pragma unroll
        for (int j = 0; j < 4; j++) s[j] = __builtin_amdgcn_readfirstlane(csr_src[i + j]);
        float ev[4], fv[4];
#pragma unroll
        for (int j = 0; j < 4; j++) ev[j] = (el + s[j] * H)[h];
#pragma unroll
        for (int j = 0; j < 4; j++) fv[j] = bf2f((fo + ((size_t)s[j] << 6))[lane]);
#pragma unroll
        for (int j = 0; j < 4; j++) {
            float v = ev[j] + erh;
            v = fmaxf(v, 0.2f * v);
            float ex = exp2_raw(v);
            if (j & 1) { s1 += ex; a1 = fmaf(ex, fv[j], a1); }
            else       { s0 += ex; a0 = fmaf(ex, fv[j], a0); }
        }
    }
    for (; i < i1; i++) {
        int s = __builtin_amdgcn_readfirstlane(csr_src[i]);
        const float* ep = el + s * H;
        float v = ep[h] + erh;
        v = fmaxf(v, 0.2f * v);
        float ex = exp2_raw(v);
        const u16* fp = fo + ((size_t)s << 6);
        float fv = bf2f(fp[lane]);
        s0 += ex;
        a0 = fmaf(ex, fv, a0);
    }

    float sumex = s0 + s1;
    float acc   = a0 + a1;
    float o;
    if (i1 > i0) o = acc * __builtin_amdgcn_rcpf(sumex) + bias[lane];   // v_rcp: ~1ulp, tol 3.9e-3
    else         o = bias[lane];                                        // 0-in-degree -> bias
    size_t idx = (size_t)n * 64 + lane;
    if constexpr (!FINAL) {
        // ELU: expm1(o) = 2^(o*log2e) - 1 (cancellation abs err ~6e-8, OK at bf16 out)
        float t = exp2_raw(o * 1.44269504088896340736f);
        o = o > 0.f ? o : (t - 1.f);
        ((u16*)outp)[idx] = f2bf_bits(o);
    } else {
        if (*flag) ((float*)outp)[idx] = o;
        else       ((u16*)outp)[idx]   = f2bf_bits(o);
    }
}

extern "C" void kernel_launch(void* const* d_in, const int* in_sizes, int n_in,
                              void* d_out, int out_size, void* d_ws, size_t ws_size,
                              hipStream_t stream)
{
    const void* h    = d_in[0];
    const int*  srcp = (const int*)d_in[1];
    const int*  dstp = (const int*)d_in[2];

    const int N  = in_sizes[0] / 128;
    const int E  = in_sizes[1];
    const int NP = (N + 1024) & ~1023;     // multiple of 1024, always covers N+1
    const int B  = NP / 1024;              // scan blocks

    // ---- workspace carve-out (~22 MB) ----
    char* ws = (char*)d_ws;
    size_t off = 0;
    auto take = [&](size_t bytes) -> char* {
        char* p = ws + off;
        off = (off + bytes + 255) & ~(size_t)255;
        return p;
    };
    float* P         = (float*)take(16960 * 4);
    int*   flag      = (int*)  take(256);
    float* el        = (float*)take((size_t)N * 4 * 4);
    float* er        = (float*)take((size_t)N * 4 * 4);
    int*   deg       = (int*)  take((size_t)NP * 4);
    int*   row_start = (int*)  take((size_t)NP * 4);   // covers N+1
    int*   rank      = (int*)  take((size_t)E * 4);
    int*   csr_src   = (int*)  take((size_t)E * 4);
    u16*   f         = (u16*)  take((size_t)N * 64 * 2);   // bf16 activations
    u16*   x1        = (u16*)  take((size_t)N * 64 * 2);
    if (off > ws_size) x1 = (u16*)d_out;   // fallback: x1 in d_out (consumed before final write)

    float* Wf0  = P;          float* Wf1  = P + 8192;  float* Wf2  = P + 12288;
    float* alf0 = P + 16384;  float* arf0 = P + 16448; float* bf0  = P + 16512;
    float* alf1 = P + 16576;  float* arf1 = P + 16640; float* bf1  = P + 16704;
    float* alf2 = P + 16768;  float* arf2 = P + 16832; float* bf2  = P + 16896;

    // 1) zero(deg) + dtype detect + param conversion, fused
    int cz_blocks = (NP + 255) / 256;
    if (cz_blocks < 67) cz_blocks = 67;
    cvt_zero_det<<<cz_blocks, 256, 0, stream>>>((const u32*)h,
        d_in[3], d_in[4], d_in[5], d_in[6],
        d_in[7], d_in[8], d_in[9], d_in[10],
        d_in[11], d_in[12], d_in[13], d_in[14], P, flag, deg, NP);

    // 2) CSR build: hist -> fused scan -> scatter
    hist_rank<<<(E + 255) / 256, 256, 0, stream>>>(dstp, deg, rank, E);
    scan_all<<<B, 256, 0, stream>>>(deg, row_start);
    scatter_kernel<<<(E + 255) / 256, 256, 0, stream>>>(srcp, dstp, rank, row_start, csr_src, E);

    int gemm_blocks = (N + 63) / 64;          // 4 waves/block, 16 cols each
    int agg_blocks  = (N * 64 + 255) / 256;   // one 64-lane wave per node

    // layer 0: 128 -> 4x16
    gemm_attn<128, 4, true ><<<gemm_blocks, 256, 0, stream>>>(flag, h,  Wf0, alf0, arf0, f, el, er, N);
    aggregate<4, false><<<agg_blocks, 256, 0, stream>>>(flag, f, el, er, row_start, csr_src, bf0, x1, N);
    // layer 1: 64 -> 4x16
    gemm_attn<64, 4, false><<<gemm_blocks, 256, 0, stream>>>(flag, x1, Wf1, alf1, arf1, f, el, er, N);
    aggregate<4, false><<<agg_blocks, 256, 0, stream>>>(flag, f, el, er, row_start, csr_src, bf1, x1, N);
    // layer 2: 64 -> 1x64 (final)
    gemm_attn<64, 1, false><<<gemm_blocks, 256, 0, stream>>>(flag, x1, Wf2, alf2, arf2, f, el, er, N);
    aggregate<1, true ><<<agg_blocks, 256, 0, stream>>>(flag, f, el, er, row_start, csr_src, bf2, d_out, N);
}